// Round 1
// baseline (353.719 us; speedup 1.0000x reference)
//
#include <hip/hip_runtime.h>
#include <math.h>

namespace {

constexpr int kT = 16384;     // time steps
constexpr int kC = 64;        // channels
constexpr int kL = 128;       // EMA kernel length
constexpr int kChunk = 128;   // timesteps per thread
constexpr float kEps = 1e-6f;

__device__ __forceinline__ float softplusf(float v) {
  return (v > 20.f) ? v : log1pf(expf(v));
}

__global__ __launch_bounds__(256) void pcen_kernel(
    const float* __restrict__ x,
    const float* __restrict__ log_alpha,
    const float* __restrict__ log_delta,
    const float* __restrict__ log_root,
    const float* __restrict__ log_s,
    float* __restrict__ out)
{
  constexpr int chunksPerRow = kT / kChunk;  // 128
  const int tid = blockIdx.x * blockDim.x + threadIdx.x;
  const int row = tid / chunksPerRow;        // row = b*C + c
  const int pos = tid - row * chunksPerRow;
  const int c = row & (kC - 1);
  const float* __restrict__ xr = x + (size_t)row * kT;
  float* __restrict__ outr = out + (size_t)row * kT;
  const int t0 = pos * kChunk;

  // ---- per-channel parameters (cheap: once per thread) ----
  const float s     = 1.f / (1.f + expf(-log_s[c]));
  const float r     = 1.f - s;                       // (1 - s)
  const float r128  = powf(r, (float)kL);            // r^128 (truncation tail)
  const float kn    = s / ((1.f - r128) + 1e-8f);    // s / (sum impulse + 1e-8)
  const float alpha = 1.f / (1.f + expf(-log_alpha[c]));
  const float delta = softplusf(log_delta[c]) + 1e-6f;
  const float root  = softplusf(log_root[c]) + 0.1f;
  const float dr    = powf(delta, root);

  // ---- init: S[t0-1] = sum_{j=0}^{127} r^j * |x[t0-1-j]| via Horner ----
  float S = 0.f;
  const int kstart = (t0 - kL) > 0 ? (t0 - kL) : 0;
  for (int k = kstart; k < t0; ++k) {
    S = fmaf(S, r, fabsf(xr[k]));
  }

  // ---- main recurrence: S[t] = r*S[t-1] + |x[t]| - r^128*|x[t-128]| ----
  #pragma unroll 4
  for (int t = t0; t < t0 + kChunk; ++t) {
    const float xm  = fabsf(xr[t]);
    const float old = (t >= kL) ? fabsf(xr[t - kL]) : 0.f;
    S = fmaf(S, r, xm);
    S = fmaf(-r128, old, S);
    const float M      = kn * S;
    const float ginv   = exp2f(-alpha * log2f(kEps + M));  // (eps+M)^-alpha
    const float normed = xm * ginv;
    const float o      = exp2f(root * log2f(normed + delta)) - dr;
    outr[t] = o;
  }
}

} // namespace

extern "C" void kernel_launch(void* const* d_in, const int* in_sizes, int n_in,
                              void* d_out, int out_size, void* d_ws, size_t ws_size,
                              hipStream_t stream) {
  const float* x  = (const float*)d_in[0];
  const float* la = (const float*)d_in[1];
  const float* ld = (const float*)d_in[2];
  const float* lr = (const float*)d_in[3];
  const float* ls = (const float*)d_in[4];
  float* out = (float*)d_out;

  constexpr int rows = 16 * 64;                 // B*C
  constexpr int chunksPerRow = 16384 / 128;     // T / kChunk
  constexpr int total = rows * chunksPerRow;    // 131072 threads
  constexpr int block = 256;
  constexpr int grid = total / block;           // 512 blocks

  hipLaunchKernelGGL(pcen_kernel, dim3(grid), dim3(block), 0, stream,
                     x, la, ld, lr, ls, out);
}

// Round 2
// 38.944 us; speedup vs baseline: 9.0828x; 9.0828x over previous
//
#include <hip/hip_runtime.h>
#include <math.h>

namespace {

constexpr int kT = 16384;     // time steps per row
constexpr int kC = 64;        // channels
constexpr int kL = 128;       // EMA kernel length (halo)
constexpr int kTileT = 8192;  // timesteps per block
constexpr int kThreads = 256;
constexpr int kChunk = kTileT / kThreads;  // 32 steps per thread
constexpr float kEps = 1e-6f;

// +1 float pad per 64: strided reads (stride 32 floats) land 2 lanes/bank (free).
__device__ __forceinline__ int pad(int g) { return g + (g >> 6); }

__device__ __forceinline__ float softplusf(float v) {
  return (v > 20.f) ? v : log1pf(expf(v));
}

__global__ __launch_bounds__(kThreads) void pcen_kernel(
    const float* __restrict__ x,
    const float* __restrict__ log_alpha,
    const float* __restrict__ log_delta,
    const float* __restrict__ log_root,
    const float* __restrict__ log_s,
    float* __restrict__ out)
{
  __shared__ float lds[8450];          // pad(8319)=8448 -> 8449 used
  __shared__ float bsum[4 + kThreads]; // chunk geometric sums (4 halo chunks)

  const int tid  = threadIdx.x;
  const int row  = blockIdx.x >> 1;    // b*C + c
  const int half = blockIdx.x & 1;
  const int tb   = half * kTileT;      // tile start within row
  const int c    = row & (kC - 1);

  const float* __restrict__ xr   = x + (size_t)row * kT;
  float* __restrict__       outr = out + (size_t)row * kT;

  // ---- per-channel parameters ----
  const float s     = 1.f / (1.f + expf(-log_s[c]));
  const float r     = 1.f - s;
  const float r32   = powf(r, 32.f);
  const float r64   = r32 * r32;
  const float r96   = r64 * r32;
  const float r128  = r64 * r64;
  const float kn    = s / ((1.f - r128) + 1e-8f);  // s / (impulse sum + 1e-8)
  const float alpha = 1.f / (1.f + expf(-log_alpha[c]));
  const float delta = softplusf(log_delta[c]) + 1e-6f;
  const float root  = softplusf(log_root[c]) + 0.1f;
  const float dr    = powf(delta, root);

  // ---- stage |x| (halo + tile) into padded LDS, coalesced float4 reads ----
  if (tid < kL / 4) {  // 32 threads load the 128-elem halo (zeros at row start)
    float4 v = make_float4(0.f, 0.f, 0.f, 0.f);
    if (half) v = *(const float4*)(xr + tb - kL + 4 * tid);
    const int l = 4 * tid;
    lds[pad(l + 0)] = fabsf(v.x);
    lds[pad(l + 1)] = fabsf(v.y);
    lds[pad(l + 2)] = fabsf(v.z);
    lds[pad(l + 3)] = fabsf(v.w);
  }
  #pragma unroll
  for (int it = 0; it < kTileT / 4 / kThreads; ++it) {  // 8 iterations
    const int m = it * kThreads + tid;
    const float4 v = *(const float4*)(xr + tb + 4 * m);
    const int l = kL + 4 * m;
    lds[pad(l + 0)] = fabsf(v.x);
    lds[pad(l + 1)] = fabsf(v.y);
    lds[pad(l + 2)] = fabsf(v.z);
    lds[pad(l + 3)] = fabsf(v.w);
  }
  __syncthreads();

  // ---- per-chunk geometric Horner sums; keep own |x| in registers ----
  float xm[kChunk];
  const int lbase = kL + tid * kChunk;
  #pragma unroll
  for (int k = 0; k < kChunk; ++k) xm[k] = lds[pad(lbase + k)];
  float Bv = 0.f;
  #pragma unroll
  for (int k = 0; k < kChunk; ++k) Bv = fmaf(Bv, r, xm[k]);
  bsum[4 + tid] = Bv;
  if (tid < 4) {  // halo chunks
    float Bh = 0.f;
    #pragma unroll
    for (int k = 0; k < kChunk; ++k) Bh = fmaf(Bh, r, lds[pad(tid * kChunk + k)]);
    bsum[tid] = Bh;
  }
  __syncthreads();

  // ---- init state S[t0-1] from the 4 preceding chunk sums ----
  float S = bsum[tid + 3];
  S = fmaf(r32, bsum[tid + 2], S);
  S = fmaf(r64, bsum[tid + 1], S);
  S = fmaf(r96, bsum[tid + 0], S);

  // ---- recurrence S[t] = r*S + |x[t]| - r^128*|x[t-128]|, + PCEN pointwise ----
  #pragma unroll
  for (int k = 0; k < kChunk; ++k) {
    const float old = lds[pad(lbase - kL + k)];   // |x[t-128]| (halo covers edge)
    const float xv  = xm[k];
    S = fmaf(S, r, xv);
    S = fmaf(-r128, old, S);
    const float M      = kn * S;
    const float ginv   = exp2f(-alpha * log2f(kEps + M));  // (eps+M)^-alpha
    const float normed = xv * ginv;
    xm[k] = exp2f(root * log2f(normed + delta)) - dr;      // outputs reuse xm regs
  }
  __syncthreads();  // all strided reads done before overwrite

  // ---- stage outputs to LDS, then coalesced float4 store ----
  #pragma unroll
  for (int k = 0; k < kChunk; ++k) lds[pad(lbase + k)] = xm[k];
  __syncthreads();

  #pragma unroll
  for (int it = 0; it < kTileT / 4 / kThreads; ++it) {
    const int m = it * kThreads + tid;
    const int l = kL + 4 * m;
    const float4 v = make_float4(lds[pad(l + 0)], lds[pad(l + 1)],
                                 lds[pad(l + 2)], lds[pad(l + 3)]);
    *(float4*)(outr + tb + 4 * m) = v;
  }
}

} // namespace

extern "C" void kernel_launch(void* const* d_in, const int* in_sizes, int n_in,
                              void* d_out, int out_size, void* d_ws, size_t ws_size,
                              hipStream_t stream) {
  const float* x  = (const float*)d_in[0];
  const float* la = (const float*)d_in[1];
  const float* ld = (const float*)d_in[2];
  const float* lr = (const float*)d_in[3];
  const float* ls = (const float*)d_in[4];
  float* out = (float*)d_out;

  constexpr int rows = 16 * 64;                  // B*C
  constexpr int blocksPerRow = kT / kTileT;      // 2
  constexpr int grid = rows * blocksPerRow;      // 2048 blocks

  hipLaunchKernelGGL(pcen_kernel, dim3(grid), dim3(kThreads), 0, stream,
                     x, la, ld, lr, ls, out);
}

// Round 3
// 36.022 us; speedup vs baseline: 9.8195x; 1.0811x over previous
//
#include <hip/hip_runtime.h>
#include <math.h>

namespace {

constexpr int kT = 16384;     // time steps per row
constexpr int kC = 64;        // channels
constexpr int kL = 128;       // EMA kernel length (halo)
constexpr int kTileT = 4096;  // timesteps per block
constexpr int kThreads = 256;
constexpr int kChunk = kTileT / kThreads;   // 16 steps per thread
constexpr int kHaloChunks = kL / kChunk;    // 8
constexpr float kEps = 1e-6f;

// Pad at float4 granularity: +1 float4 per 64-float block. Keeps 16B alignment
// for ds_*_b128 while skewing banks across the strided per-thread accesses.
__device__ __forceinline__ int pad4(int g) { return g + ((g >> 6) << 2); }

__device__ __forceinline__ float softplusf(float v) {
  return (v > 20.f) ? v : log1pf(expf(v));
}

__global__ __launch_bounds__(kThreads, 8) void pcen_kernel(
    const float* __restrict__ x,
    const float* __restrict__ log_alpha,
    const float* __restrict__ log_delta,
    const float* __restrict__ log_root,
    const float* __restrict__ log_s,
    float* __restrict__ out)
{
  __shared__ alignas(16) float lds[4484];          // pad4(4220)+4
  __shared__ float bsum[kHaloChunks + kThreads];   // chunk geometric sums

  const int tid  = threadIdx.x;
  const int row  = blockIdx.x >> 2;     // b*C + c
  const int quad = blockIdx.x & 3;
  const int tb   = quad * kTileT;       // tile start within row
  const int c    = row & (kC - 1);

  const float* __restrict__ xr   = x + (size_t)row * kT;
  float* __restrict__       outr = out + (size_t)row * kT;

  // ---- per-channel parameters ----
  const float s    = 1.f / (1.f + expf(-log_s[c]));
  const float r    = 1.f - s;
  const float r2   = r * r;
  const float r4   = r2 * r2;
  const float r8   = r4 * r4;
  const float r16  = r8 * r8;
  const float r32  = r16 * r16;
  const float r64  = r32 * r32;
  const float r128 = r64 * r64;
  const float kn   = s / ((1.f - r128) + 1e-8f);   // s / (impulse sum + 1e-8)
  const float alpha = 1.f / (1.f + expf(-log_alpha[c]));
  const float delta = softplusf(log_delta[c]) + 1e-6f;
  const float root  = softplusf(log_root[c]) + 0.1f;
  const float dr    = powf(delta, root);

  // ---- stage |x| (halo + tile) into padded LDS, all float4 ----
  if (tid < kL / 4) {  // 32 threads: 128-elem halo (zeros at row start)
    float4 v = make_float4(0.f, 0.f, 0.f, 0.f);
    if (tb) v = *(const float4*)(xr + tb - kL + 4 * tid);
    float4 a = make_float4(fabsf(v.x), fabsf(v.y), fabsf(v.z), fabsf(v.w));
    *(float4*)&lds[pad4(4 * tid)] = a;
  }
  #pragma unroll
  for (int it = 0; it < kTileT / 4 / kThreads; ++it) {  // 4 iterations
    const int m = it * kThreads + tid;
    const float4 v = *(const float4*)(xr + tb + 4 * m);
    float4 a = make_float4(fabsf(v.x), fabsf(v.y), fabsf(v.z), fabsf(v.w));
    *(float4*)&lds[pad4(kL + 4 * m)] = a;
  }
  __syncthreads();

  // ---- read own chunk (float4s), per-chunk geometric Horner sum ----
  float xm[kChunk];
  const int lbase = kL + tid * kChunk;
  #pragma unroll
  for (int q = 0; q < kChunk / 4; ++q) {
    const float4 v = *(const float4*)&lds[pad4(lbase + 4 * q)];
    xm[4 * q + 0] = v.x; xm[4 * q + 1] = v.y;
    xm[4 * q + 2] = v.z; xm[4 * q + 3] = v.w;
  }
  float Bv = 0.f;
  #pragma unroll
  for (int k = 0; k < kChunk; ++k) Bv = fmaf(Bv, r, xm[k]);
  bsum[kHaloChunks + tid] = Bv;
  if (tid < kHaloChunks) {  // 8 halo chunks
    float Bh = 0.f;
    const int hbase = tid * kChunk;
    #pragma unroll
    for (int q = 0; q < kChunk / 4; ++q) {
      const float4 v = *(const float4*)&lds[pad4(hbase + 4 * q)];
      Bh = fmaf(Bh, r, v.x); Bh = fmaf(Bh, r, v.y);
      Bh = fmaf(Bh, r, v.z); Bh = fmaf(Bh, r, v.w);
    }
    bsum[tid] = Bh;
  }
  __syncthreads();

  // ---- init S[t0-1] from the 8 preceding chunk sums (Horner over r^16) ----
  float S = bsum[tid];
  #pragma unroll
  for (int m = 1; m < kHaloChunks; ++m) S = fmaf(S, r16, bsum[tid + m]);

  // ---- recurrence S[t] = r*S + |x[t]| - r^128*|x[t-128]| + PCEN pointwise ----
  #pragma unroll
  for (int q = 0; q < kChunk / 4; ++q) {
    const float4 ov = *(const float4*)&lds[pad4(lbase - kL + 4 * q)];
    const float olds[4] = {ov.x, ov.y, ov.z, ov.w};
    #pragma unroll
    for (int j = 0; j < 4; ++j) {
      const int k = 4 * q + j;
      const float xv = xm[k];
      S = fmaf(S, r, xv);
      S = fmaf(-r128, olds[j], S);
      const float M      = kn * S;
      const float ginv   = exp2f(-alpha * log2f(kEps + M));  // (eps+M)^-alpha
      const float normed = xv * ginv;
      xm[k] = exp2f(root * log2f(normed + delta)) - dr;
    }
  }
  __syncthreads();  // strided old-reads done before overwrite

  // ---- stage outputs to LDS (float4), then coalesced float4 store ----
  #pragma unroll
  for (int q = 0; q < kChunk / 4; ++q) {
    float4 v = make_float4(xm[4 * q + 0], xm[4 * q + 1],
                           xm[4 * q + 2], xm[4 * q + 3]);
    *(float4*)&lds[pad4(lbase + 4 * q)] = v;
  }
  __syncthreads();

  #pragma unroll
  for (int it = 0; it < kTileT / 4 / kThreads; ++it) {
    const int m = it * kThreads + tid;
    const float4 v = *(const float4*)&lds[pad4(kL + 4 * m)];
    *(float4*)(outr + tb + 4 * m) = v;
  }
}

} // namespace

extern "C" void kernel_launch(void* const* d_in, const int* in_sizes, int n_in,
                              void* d_out, int out_size, void* d_ws, size_t ws_size,
                              hipStream_t stream) {
  const float* x  = (const float*)d_in[0];
  const float* la = (const float*)d_in[1];
  const float* ld = (const float*)d_in[2];
  const float* lr = (const float*)d_in[3];
  const float* ls = (const float*)d_in[4];
  float* out = (float*)d_out;

  constexpr int rows = 16 * 64;                  // B*C
  constexpr int blocksPerRow = kT / kTileT;      // 4
  constexpr int grid = rows * blocksPerRow;      // 4096 blocks

  hipLaunchKernelGGL(pcen_kernel, dim3(grid), dim3(kThreads), 0, stream,
                     x, la, ld, lr, ls, out);
}

// Round 4
// 30.169 us; speedup vs baseline: 11.7245x; 1.1940x over previous
//
#include <hip/hip_runtime.h>
#include <math.h>

namespace {

constexpr int kT = 16384;     // time steps per row
constexpr int kC = 64;        // channels
constexpr int kL = 128;       // EMA kernel length (halo)
constexpr int kTileT = 4096;  // timesteps per block
constexpr int kThreads = 256;
constexpr int kChunk = kTileT / kThreads;   // 16 steps per thread
constexpr int kHaloChunks = kL / kChunk;    // 8
constexpr float kEps = 1e-6f;

// Pad at float4 granularity: +1 float4 per 64-float block. Keeps 16B alignment
// for ds_*_b128 while skewing banks across the strided per-thread accesses.
__device__ __forceinline__ int pad4(int g) { return g + ((g >> 6) << 2); }

__device__ __forceinline__ float softplusf(float v) {
  return (v > 20.f) ? v : log1pf(expf(v));
}

// Single-instruction HW transcendentals (v_exp_f32 / v_log_f32, ~1 ULP).
// Args here are bounded away from singular points -> error << 0.08 threshold.
__device__ __forceinline__ float fexp2(float v) { return __builtin_amdgcn_exp2f(v); }
__device__ __forceinline__ float flog2(float v) { return __builtin_amdgcn_logf(v); }

__global__ __launch_bounds__(kThreads, 8) void pcen_kernel(
    const float* __restrict__ x,
    const float* __restrict__ log_alpha,
    const float* __restrict__ log_delta,
    const float* __restrict__ log_root,
    const float* __restrict__ log_s,
    float* __restrict__ out)
{
  __shared__ alignas(16) float lds[4484];          // pad4(4220)+4
  __shared__ float bsum[kHaloChunks + kThreads];   // chunk geometric sums

  const int tid  = threadIdx.x;
  const int row  = blockIdx.x >> 2;     // b*C + c
  const int quad = blockIdx.x & 3;
  const int tb   = quad * kTileT;       // tile start within row
  const int c    = row & (kC - 1);

  const float* __restrict__ xr   = x + (size_t)row * kT;
  float* __restrict__       outr = out + (size_t)row * kT;

  // ---- per-channel parameters (once per thread; precision not critical path) ----
  const float s    = 1.f / (1.f + expf(-log_s[c]));
  const float r    = 1.f - s;
  const float r2   = r * r;
  const float r4   = r2 * r2;
  const float r8   = r4 * r4;
  const float r16  = r8 * r8;
  const float r32  = r16 * r16;
  const float r64  = r32 * r32;
  const float r128 = r64 * r64;
  const float kn   = s / ((1.f - r128) + 1e-8f);   // s / (impulse sum + 1e-8)
  const float alpha = 1.f / (1.f + expf(-log_alpha[c]));
  const float delta = softplusf(log_delta[c]) + 1e-6f;
  const float root  = softplusf(log_root[c]) + 0.1f;
  const float dr    = powf(delta, root);

  // ---- stage |x| (halo + tile) into padded LDS, all float4 ----
  if (tid < kL / 4) {  // 32 threads: 128-elem halo (zeros at row start)
    float4 v = make_float4(0.f, 0.f, 0.f, 0.f);
    if (tb) v = *(const float4*)(xr + tb - kL + 4 * tid);
    float4 a = make_float4(fabsf(v.x), fabsf(v.y), fabsf(v.z), fabsf(v.w));
    *(float4*)&lds[pad4(4 * tid)] = a;
  }
  #pragma unroll
  for (int it = 0; it < kTileT / 4 / kThreads; ++it) {  // 4 iterations
    const int m = it * kThreads + tid;
    const float4 v = *(const float4*)(xr + tb + 4 * m);
    float4 a = make_float4(fabsf(v.x), fabsf(v.y), fabsf(v.z), fabsf(v.w));
    *(float4*)&lds[pad4(kL + 4 * m)] = a;
  }
  __syncthreads();

  // ---- read own chunk (float4s), per-chunk geometric Horner sum ----
  float xm[kChunk];
  const int lbase = kL + tid * kChunk;
  #pragma unroll
  for (int q = 0; q < kChunk / 4; ++q) {
    const float4 v = *(const float4*)&lds[pad4(lbase + 4 * q)];
    xm[4 * q + 0] = v.x; xm[4 * q + 1] = v.y;
    xm[4 * q + 2] = v.z; xm[4 * q + 3] = v.w;
  }
  float Bv = 0.f;
  #pragma unroll
  for (int k = 0; k < kChunk; ++k) Bv = fmaf(Bv, r, xm[k]);
  bsum[kHaloChunks + tid] = Bv;
  if (tid < kHaloChunks) {  // 8 halo chunks
    float Bh = 0.f;
    const int hbase = tid * kChunk;
    #pragma unroll
    for (int q = 0; q < kChunk / 4; ++q) {
      const float4 v = *(const float4*)&lds[pad4(hbase + 4 * q)];
      Bh = fmaf(Bh, r, v.x); Bh = fmaf(Bh, r, v.y);
      Bh = fmaf(Bh, r, v.z); Bh = fmaf(Bh, r, v.w);
    }
    bsum[tid] = Bh;
  }
  __syncthreads();

  // ---- init S[t0-1] from the 8 preceding chunk sums (Horner over r^16) ----
  float S = bsum[tid];
  #pragma unroll
  for (int m = 1; m < kHaloChunks; ++m) S = fmaf(S, r16, bsum[tid + m]);

  // ---- recurrence S[t] = r*S + |x[t]| - r^128*|x[t-128]| + PCEN pointwise ----
  #pragma unroll
  for (int q = 0; q < kChunk / 4; ++q) {
    const float4 ov = *(const float4*)&lds[pad4(lbase - kL + 4 * q)];
    const float olds[4] = {ov.x, ov.y, ov.z, ov.w};
    #pragma unroll
    for (int j = 0; j < 4; ++j) {
      const int k = 4 * q + j;
      const float xv = xm[k];
      S = fmaf(S, r, xv);
      S = fmaf(-r128, olds[j], S);
      const float M      = kn * S;
      const float ginv   = fexp2(-alpha * flog2(kEps + M));  // (eps+M)^-alpha
      const float normed = xv * ginv;
      xm[k] = fexp2(root * flog2(normed + delta)) - dr;
    }
  }
  __syncthreads();  // strided old-reads done before overwrite

  // ---- stage outputs to LDS (float4), then coalesced float4 store ----
  #pragma unroll
  for (int q = 0; q < kChunk / 4; ++q) {
    float4 v = make_float4(xm[4 * q + 0], xm[4 * q + 1],
                           xm[4 * q + 2], xm[4 * q + 3]);
    *(float4*)&lds[pad4(lbase + 4 * q)] = v;
  }
  __syncthreads();

  #pragma unroll
  for (int it = 0; it < kTileT / 4 / kThreads; ++it) {
    const int m = it * kThreads + tid;
    const float4 v = *(const float4*)&lds[pad4(kL + 4 * m)];
    *(float4*)(outr + tb + 4 * m) = v;
  }
}

} // namespace

extern "C" void kernel_launch(void* const* d_in, const int* in_sizes, int n_in,
                              void* d_out, int out_size, void* d_ws, size_t ws_size,
                              hipStream_t stream) {
  const float* x  = (const float*)d_in[0];
  const float* la = (const float*)d_in[1];
  const float* ld = (const float*)d_in[2];
  const float* lr = (const float*)d_in[3];
  const float* ls = (const float*)d_in[4];
  float* out = (float*)d_out;

  constexpr int rows = 16 * 64;                  // B*C
  constexpr int blocksPerRow = kT / kTileT;      // 4
  constexpr int grid = rows * blocksPerRow;      // 4096 blocks

  hipLaunchKernelGGL(pcen_kernel, dim3(grid), dim3(kThreads), 0, stream,
                     x, la, ld, lr, ls, out);
}

// Round 5
// 26.434 us; speedup vs baseline: 13.3813x; 1.1413x over previous
//
#include <hip/hip_runtime.h>
#include <math.h>

namespace {

constexpr int kT = 16384;     // time steps per row
constexpr int kC = 64;        // channels
constexpr int kL = 128;       // EMA kernel length (halo)
constexpr int kSub = 2048;    // sub-tile (pipelined unit)
constexpr int kSpan = 2 * kSub;             // per-block span = 4096
constexpr int kThreads = 256;
constexpr int kChunk = kSub / kThreads;     // 8 steps per thread per sub-tile
constexpr int kHaloChunks = kL / kChunk;    // 16
constexpr int kBufF = 2312;                 // pad4(kL + kSub) = 2176 + 136
constexpr float kEps = 1e-6f;

// Pad at float4 granularity: +1 float4 per 64 floats. Keeps 16B alignment
// for ds_*_b128 while skewing banks across strided per-thread accesses.
__device__ __forceinline__ int pad4(int g) { return g + ((g >> 6) << 2); }

// Single-instruction HW transcendentals (v_exp_f32 / v_log_f32, ~1 ULP).
__device__ __forceinline__ float fexp2(float v) { return __builtin_amdgcn_exp2f(v); }
__device__ __forceinline__ float flog2(float v) { return __builtin_amdgcn_logf(v); }

constexpr float kLog2e  = 1.4426950408889634f;
constexpr float kRlog2e = 0.6931471805599453f;

__device__ __forceinline__ float fsigmoid(float z) {
  return 1.f / (1.f + fexp2(-z * kLog2e));
}
__device__ __forceinline__ float fsoftplus(float v) {  // args here are O(1)
  return flog2(1.f + fexp2(v * kLog2e)) * kRlog2e;
}

__device__ __forceinline__ float4 ld4g(const float* p) { return *(const float4*)p; }
__device__ __forceinline__ float4 ld4s(const float* b, int g) { return *(const float4*)&b[g]; }
__device__ __forceinline__ void st4s(float* b, int g, float4 v) { *(float4*)&b[g] = v; }

__global__ __launch_bounds__(kThreads, 8) void pcen_kernel(
    const float* __restrict__ x,
    const float* __restrict__ log_alpha,
    const float* __restrict__ log_delta,
    const float* __restrict__ log_root,
    const float* __restrict__ log_s,
    float* __restrict__ out)
{
  __shared__ alignas(16) float A[kBufF];   // sub-tile 0: [halo 128][2048]
  __shared__ alignas(16) float Bb[kBufF];  // sub-tile 1: [halo 128][2048]
  __shared__ float bsum[kHaloChunks + kThreads];  // reused for both sub-tiles

  const int tid = threadIdx.x;
  const int row = blockIdx.x >> 2;    // b*C + c
  const int q   = blockIdx.x & 3;
  const int tb  = q * kSpan;          // span start within row
  const int c   = row & (kC - 1);

  const float* __restrict__ xr   = x + (size_t)row * kT;
  float* __restrict__       outr = out + (size_t)row * kT;

  // ---- per-channel parameters (all single-inst transcendentals) ----
  const float s    = fsigmoid(log_s[c]);
  const float r    = 1.f - s;
  const float r2   = r * r;
  const float r4   = r2 * r2;
  const float r8   = r4 * r4;
  const float r16  = r8 * r8;
  const float r32  = r16 * r16;
  const float r64  = r32 * r32;
  const float r128 = r64 * r64;
  const float kn   = s / ((1.f - r128) + 1e-8f);   // s / (impulse sum + 1e-8)
  const float alpha = fsigmoid(log_alpha[c]);
  const float delta = fsoftplus(log_delta[c]) + 1e-6f;
  const float root  = fsoftplus(log_root[c]) + 0.1f;
  const float dr    = fexp2(root * flog2(delta));  // delta^root

  const int lbase = kL + tid * kChunk;

  // ================= P0: load sub0 (+halo) -> regs -> A =================
  float4 h0 = make_float4(0.f, 0.f, 0.f, 0.f);
  if (tid < kL / 4) { if (tb) h0 = ld4g(xr + tb - kL + 4 * tid); }
  const float4 v0a = ld4g(xr + tb + 4 * tid);
  const float4 v0b = ld4g(xr + tb + 1024 + 4 * tid);
  if (tid < kL / 4) st4s(A, pad4(4 * tid), h0);
  st4s(A, pad4(kL + 4 * tid), v0a);
  st4s(A, pad4(kL + 1024 + 4 * tid), v0b);
  __syncthreads();

  // ========== P1: issue sub1 global loads (prefetch); Horner sub0 ==========
  float4 h1 = make_float4(0.f, 0.f, 0.f, 0.f);
  if (tid < kL / 4) h1 = ld4g(xr + tb + kSub - kL + 4 * tid);
  const float4 v1a = ld4g(xr + tb + kSub + 4 * tid);
  const float4 v1b = ld4g(xr + tb + kSub + 1024 + 4 * tid);

  float xm[kChunk];
  {
    const float4 a0 = ld4s(A, pad4(lbase));
    const float4 a1 = ld4s(A, pad4(lbase + 4));
    xm[0]=a0.x; xm[1]=a0.y; xm[2]=a0.z; xm[3]=a0.w;
    xm[4]=a1.x; xm[5]=a1.y; xm[6]=a1.z; xm[7]=a1.w;
  }
  float Bv = 0.f;
  #pragma unroll
  for (int k = 0; k < kChunk; ++k) Bv = fmaf(Bv, r, fabsf(xm[k]));
  bsum[kHaloChunks + tid] = Bv;
  if (tid < kHaloChunks) {
    const float4 ha = ld4s(A, pad4(tid * kChunk));
    const float4 hb = ld4s(A, pad4(tid * kChunk + 4));
    float Bh = fabsf(ha.x);
    Bh = fmaf(Bh, r, fabsf(ha.y)); Bh = fmaf(Bh, r, fabsf(ha.z));
    Bh = fmaf(Bh, r, fabsf(ha.w)); Bh = fmaf(Bh, r, fabsf(hb.x));
    Bh = fmaf(Bh, r, fabsf(hb.y)); Bh = fmaf(Bh, r, fabsf(hb.z));
    Bh = fmaf(Bh, r, fabsf(hb.w));
    bsum[tid] = Bh;
  }
  __syncthreads();

  // ================= P2: init S, recurrence + PCEN on sub0 =================
  float S = bsum[tid];
  #pragma unroll
  for (int m = 1; m < kHaloChunks; ++m) S = fmaf(S, r8, bsum[tid + m]);
  #pragma unroll
  for (int q2 = 0; q2 < kChunk / 4; ++q2) {
    const float4 ov = ld4s(A, pad4(tid * kChunk + 4 * q2));  // |x[t-128]| source
    const float olds[4] = {ov.x, ov.y, ov.z, ov.w};
    #pragma unroll
    for (int j = 0; j < 4; ++j) {
      const int k = 4 * q2 + j;
      const float xv = fabsf(xm[k]);             // abs folds to VOP3 modifier
      S = fmaf(S, r, xv);
      S = fmaf(-r128, fabsf(olds[j]), S);
      const float M      = kn * S;
      const float ginv   = fexp2(-alpha * flog2(kEps + M));
      const float normed = xv * ginv;
      xm[k] = fexp2(root * flog2(normed + delta)) - dr;
    }
  }
  __syncthreads();  // sub0 old-reads done; bsum consumed

  // ===== P3: write prefetched sub1 regs -> B; write sub0 outputs -> A =====
  if (tid < kL / 4) st4s(Bb, pad4(4 * tid), h1);
  st4s(Bb, pad4(kL + 4 * tid), v1a);
  st4s(Bb, pad4(kL + 1024 + 4 * tid), v1b);
  st4s(A, pad4(lbase),     make_float4(xm[0], xm[1], xm[2], xm[3]));
  st4s(A, pad4(lbase + 4), make_float4(xm[4], xm[5], xm[6], xm[7]));
  __syncthreads();

  // ======= P4: coalesced store sub0 (overlaps rest); Horner sub1 =======
  {
    const float4 o0 = ld4s(A, pad4(kL + 4 * tid));
    const float4 o1 = ld4s(A, pad4(kL + 1024 + 4 * tid));
    *(float4*)(outr + tb + 4 * tid) = o0;
    *(float4*)(outr + tb + 1024 + 4 * tid) = o1;
  }
  {
    const float4 a0 = ld4s(Bb, pad4(lbase));
    const float4 a1 = ld4s(Bb, pad4(lbase + 4));
    xm[0]=a0.x; xm[1]=a0.y; xm[2]=a0.z; xm[3]=a0.w;
    xm[4]=a1.x; xm[5]=a1.y; xm[6]=a1.z; xm[7]=a1.w;
  }
  Bv = 0.f;
  #pragma unroll
  for (int k = 0; k < kChunk; ++k) Bv = fmaf(Bv, r, fabsf(xm[k]));
  bsum[kHaloChunks + tid] = Bv;
  if (tid < kHaloChunks) {
    const float4 ha = ld4s(Bb, pad4(tid * kChunk));
    const float4 hb = ld4s(Bb, pad4(tid * kChunk + 4));
    float Bh = fabsf(ha.x);
    Bh = fmaf(Bh, r, fabsf(ha.y)); Bh = fmaf(Bh, r, fabsf(ha.z));
    Bh = fmaf(Bh, r, fabsf(ha.w)); Bh = fmaf(Bh, r, fabsf(hb.x));
    Bh = fmaf(Bh, r, fabsf(hb.y)); Bh = fmaf(Bh, r, fabsf(hb.z));
    Bh = fmaf(Bh, r, fabsf(hb.w));
    bsum[tid] = Bh;
  }
  __syncthreads();

  // ================= P5: init S, recurrence + PCEN on sub1 =================
  S = bsum[tid];
  #pragma unroll
  for (int m = 1; m < kHaloChunks; ++m) S = fmaf(S, r8, bsum[tid + m]);
  #pragma unroll
  for (int q2 = 0; q2 < kChunk / 4; ++q2) {
    const float4 ov = ld4s(Bb, pad4(tid * kChunk + 4 * q2));
    const float olds[4] = {ov.x, ov.y, ov.z, ov.w};
    #pragma unroll
    for (int j = 0; j < 4; ++j) {
      const int k = 4 * q2 + j;
      const float xv = fabsf(xm[k]);
      S = fmaf(S, r, xv);
      S = fmaf(-r128, fabsf(olds[j]), S);
      const float M      = kn * S;
      const float ginv   = fexp2(-alpha * flog2(kEps + M));
      const float normed = xv * ginv;
      xm[k] = fexp2(root * flog2(normed + delta)) - dr;
    }
  }
  __syncthreads();  // sub1 old-reads done

  // ============== P6: outputs -> B, bar, coalesced store sub1 ==============
  st4s(Bb, pad4(lbase),     make_float4(xm[0], xm[1], xm[2], xm[3]));
  st4s(Bb, pad4(lbase + 4), make_float4(xm[4], xm[5], xm[6], xm[7]));
  __syncthreads();
  {
    const float4 o0 = ld4s(Bb, pad4(kL + 4 * tid));
    const float4 o1 = ld4s(Bb, pad4(kL + 1024 + 4 * tid));
    *(float4*)(outr + tb + kSub + 4 * tid) = o0;
    *(float4*)(outr + tb + kSub + 1024 + 4 * tid) = o1;
  }
}

} // namespace

extern "C" void kernel_launch(void* const* d_in, const int* in_sizes, int n_in,
                              void* d_out, int out_size, void* d_ws, size_t ws_size,
                              hipStream_t stream) {
  const float* x  = (const float*)d_in[0];
  const float* la = (const float*)d_in[1];
  const float* ld = (const float*)d_in[2];
  const float* lr = (const float*)d_in[3];
  const float* ls = (const float*)d_in[4];
  float* out = (float*)d_out;

  constexpr int rows = 16 * 64;              // B*C
  constexpr int blocksPerRow = kT / kSpan;   // 4
  constexpr int grid = rows * blocksPerRow;  // 4096 blocks

  hipLaunchKernelGGL(pcen_kernel, dim3(grid), dim3(kThreads), 0, stream,
                     x, la, ld, lr, ls, out);
}